// Round 13
// baseline (31.843 us; speedup 1.0000x reference)
//
#include <hip/hip_runtime.h>

#define NPTS  4096
#define BQ    16
#define NT    256
#define SEG   4
#define SEGN  (NPTS / SEG)       // 1024 inner points per segment
#define NT32  (SEGN / 32)        // 32 inner tiles (32 points each)
#define WC    4                  // column-tiles (32 cols each) per wave
#define WCOLS (WC * 32)          // 128 cols per wave
#define BCOLS (4 * WCOLS)        // 512 cols per block (4 waves)
#define NCOMB 128                // comb blocks

typedef short bhalf8   __attribute__((ext_vector_type(8)));   // 8 bf16 (4 VGPRs)
typedef float floatx16 __attribute__((ext_vector_type(16)));  // 32x32 MFMA acc

__device__ __forceinline__ short f2bf(float f) {
    unsigned u = __float_as_uint(f);
    unsigned r = (u + 0x7FFFu + ((u >> 16) & 1u)) >> 16;   // RNE
    return (short)r;
}
__device__ __forceinline__ float bf2f(short s) {
    return __uint_as_float(((unsigned)(unsigned short)s) << 16);
}
__device__ __forceinline__ int imin(int a, int b) { return a < b ? a : b; }

// Pass 1 (MFMA 32x32x16): D[i][j] = dist2(x_i,y_j) + 1  (bias makes all
// values strictly positive -> int32 bit-compare == float compare).
//   A row i: g0=[ah(3),al(3),xxh,xxl], g1=[ah(3),al(3),1,1]   (a=-2x)
//   B col j: g0=[yh(3),yh(3),1,1],     g1=[yl(3),yl(3),vh,vl] (v=yy+1 split)
// Epilogue: INTEGER min tree (bitcast, no asm near MFMA dests) -> LLVM fuses
// smin chains to v_min3_i32 (8 inst/MFMA vs 16 f32 mins).
// Per-col result combined globally via uint atomicMin (commutative, bitwise
// deterministic). partial[] is memset to 0x7F7F7F7F (3.39e38) per launch.
// grid (8, 4, 32) = 1024 blocks.
__global__ __launch_bounds__(NT, 2)
void chamfer_mfma_kernel(const float* __restrict__ preds,
                         const float* __restrict__ gts,
                         unsigned int* __restrict__ partial,
                         unsigned long long* __restrict__ acc)
{
    __shared__ bhalf8 s_frag[NT32 * 64];   // 32 KB

    const int cb  = blockIdx.x;   // 0..7
    const int seg = blockIdx.y;   // 0..3
    const int bd  = blockIdx.z;   // 0..31
    const int dir = bd >> 4;
    const int b   = bd & 15;

    if (cb == 0 && seg == 0 && bd == 0 && threadIdx.x < 2)
        acc[threadIdx.x] = 0ULL;   // [0]=fixed-point sum, [1]=ticket counter

    const float* outer = (dir == 0) ? preds : gts;
    const float* inner = (dir == 0) ? gts   : preds;
    const float* ob = outer + (size_t)b * NPTS * 3;
    const float* ib = inner + (size_t)b * NPTS * 3 + (size_t)seg * SEGN * 3;

    const short one = (short)0x3F80;   // bf16 1.0

    // ---- stage A fragments (inner points) ----
    for (int p = (int)threadIdx.x; p < SEGN; p += NT) {
        const float x0 = ib[p * 3 + 0], x1 = ib[p * 3 + 1], x2 = ib[p * 3 + 2];
        const float a0 = -2.0f * x0, a1 = -2.0f * x1, a2 = -2.0f * x2;
        const short h0 = f2bf(a0), h1 = f2bf(a1), h2 = f2bf(a2);
        const short l0 = f2bf(a0 - bf2f(h0));
        const short l1 = f2bf(a1 - bf2f(h1));
        const short l2 = f2bf(a2 - bf2f(h2));
        const float xx = x0 * x0 + x1 * x1 + x2 * x2;
        const short xh = f2bf(xx);
        const short xl = f2bf(xx - bf2f(xh));
        bhalf8 e0, e1;
        e0[0] = h0; e0[1] = h1; e0[2] = h2; e0[3] = l0;
        e0[4] = l1; e0[5] = l2; e0[6] = xh;  e0[7] = xl;
        e1[0] = h0; e1[1] = h1; e1[2] = h2; e1[3] = l0;
        e1[4] = l1; e1[5] = l2; e1[6] = one; e1[7] = one;
        const int t = p >> 5, r = p & 31;
        s_frag[t * 64 + r]      = e0;   // k-group 0 rows (lanes 0-31)
        s_frag[t * 64 + 32 + r] = e1;   // k-group 1 rows (lanes 32-63)
    }

    const int wv   = (int)threadIdx.x >> 6;
    const int lane = (int)threadIdx.x & 63;
    const int g    = lane >> 5;          // k-group 0..1
    const int colbase = cb * BCOLS + wv * WCOLS;

    bhalf8 bfrag[WC];
#pragma unroll
    for (int ct = 0; ct < WC; ++ct) {
        const int col = colbase + ct * 32 + (lane & 31);
        const float y0 = ob[col * 3 + 0], y1 = ob[col * 3 + 1], y2 = ob[col * 3 + 2];
        const short h0 = f2bf(y0), h1 = f2bf(y1), h2 = f2bf(y2);
        bhalf8 f;
        if (g == 0) {          // k 0-7: [yh(3), yh(3), 1, 1]
            f[0] = h0; f[1] = h1; f[2] = h2; f[3] = h0; f[4] = h1; f[5] = h2;
            f[6] = one; f[7] = one;
        } else {               // k 8-15: [yl(3), yl(3), vh, vl], v = yy + 1
            const short q0 = f2bf(y0 - bf2f(h0));
            const short q1 = f2bf(y1 - bf2f(h1));
            const short q2 = f2bf(y2 - bf2f(h2));
            const float v = y0 * y0 + y1 * y1 + y2 * y2 + 1.0f;
            const short vh = f2bf(v);
            const short vl = f2bf(v - bf2f(vh));
            f[0] = q0; f[1] = q1; f[2] = q2; f[3] = q0; f[4] = q1; f[5] = q2;
            f[6] = vh; f[7] = vl;
        }
        bfrag[ct] = f;
    }
    __syncthreads();

    int accm[WC];
#pragma unroll
    for (int ct = 0; ct < WC; ++ct) accm[ct] = 0x7F7F7F7F;   // large positive float bits

    const floatx16 zacc = {0,0,0,0,0,0,0,0,0,0,0,0,0,0,0,0};

#pragma unroll 2
    for (int t = 0; t < NT32; ++t) {
        const bhalf8 a = s_frag[t * 64 + lane];
#pragma unroll
        for (int ct = 0; ct < WC; ++ct) {
            const floatx16 c = __builtin_amdgcn_mfma_f32_32x32x16_bf16(a, bfrag[ct], zacc, 0, 0, 0);
            // integer min tree over positive-float bits -> v_min3_i32 fusion
            const int x0  = __float_as_int(c[0]),  x1  = __float_as_int(c[1]);
            const int x2  = __float_as_int(c[2]),  x3  = __float_as_int(c[3]);
            const int x4  = __float_as_int(c[4]),  x5  = __float_as_int(c[5]);
            const int x6  = __float_as_int(c[6]),  x7  = __float_as_int(c[7]);
            const int x8  = __float_as_int(c[8]),  x9  = __float_as_int(c[9]);
            const int x10 = __float_as_int(c[10]), x11 = __float_as_int(c[11]);
            const int x12 = __float_as_int(c[12]), x13 = __float_as_int(c[13]);
            const int x14 = __float_as_int(c[14]), x15 = __float_as_int(c[15]);
            const int ta = imin(imin(x0,  x1),  x2);
            const int tb = imin(imin(x3,  x4),  x5);
            const int tc = imin(imin(x6,  x7),  x8);
            const int td = imin(imin(x9,  x10), x11);
            const int te = imin(imin(x12, x13), x14);
            const int tf = imin(imin(ta, tb), x15);
            const int tg = imin(imin(tc, td), te);
            accm[ct] = imin(imin(tf, tg), accm[ct]);
        }
    }

#pragma unroll
    for (int ct = 0; ct < WC; ++ct) {
        int v = accm[ct];
        v = imin(v, __shfl_xor(v, 32, 64));
        if (lane < 32) {
            const int col = colbase + ct * 32 + lane;
            atomicMin(&partial[(size_t)bd * NPTS + col], (unsigned int)v);
        }
    }
}

// Pass 2: 131072 uint slots (final per-col mins, biased +1); bitcast, sum,
// int64 fixed-point atomicAdd (bitwise deterministic); last block writes
// out = total/(B*N) - 2 (removes the +1 bias on both directions).
__global__ __launch_bounds__(NT)
void chamfer_comb_kernel(const unsigned int* __restrict__ partial,
                         unsigned long long* __restrict__ acc,
                         float* __restrict__ out)
{
    __shared__ float s_red[NT];
    const uint4 p = ((const uint4*)partial)[(int)blockIdx.x * NT + (int)threadIdx.x];
    float sum = __uint_as_float(p.x) + __uint_as_float(p.y)
              + __uint_as_float(p.z) + __uint_as_float(p.w);
    s_red[threadIdx.x] = sum;
    __syncthreads();
#pragma unroll
    for (int s = NT / 2; s > 0; s >>= 1) {
        if ((int)threadIdx.x < s) s_red[threadIdx.x] += s_red[threadIdx.x + s];
        __syncthreads();
    }
    if (threadIdx.x == 0) {
        const long long fx = (long long)llrint((double)s_red[0] * 4294967296.0);
        atomicAdd(&acc[0], (unsigned long long)fx);
        __threadfence();
        const unsigned long long t = atomicAdd(&acc[1], 1ULL);
        if (t == (unsigned long long)(NCOMB - 1)) {
            const unsigned long long total = atomicAdd(&acc[0], 0ULL);
            const double v = (double)(long long)total *
                             (1.0 / 4294967296.0) * (1.0 / (double)(BQ * NPTS)) - 2.0;
            out[0] = (float)v;
        }
    }
}

extern "C" void kernel_launch(void* const* d_in, const int* in_sizes, int n_in,
                              void* d_out, int out_size, void* d_ws, size_t ws_size,
                              hipStream_t stream)
{
    const float* preds = (const float*)d_in[0];
    const float* gts   = (const float*)d_in[1];
    float* out = (float*)d_out;
    unsigned int* partial = (unsigned int*)d_ws;                 // 131072 u32 = 0.5 MB
    unsigned long long* acc =
        (unsigned long long*)(partial + (size_t)2 * BQ * NPTS);  // +2 u64

    // init per-col mins to huge positive float bits (re-done every launch)
    hipMemsetAsync(partial, 0x7F, (size_t)2 * BQ * NPTS * sizeof(unsigned int), stream);

    dim3 grid1(NPTS / BCOLS, SEG, 2 * BQ);   // (8, 4, 32) = 1024 blocks
    chamfer_mfma_kernel<<<grid1, NT, 0, stream>>>(preds, gts, partial, acc);
    chamfer_comb_kernel<<<NCOMB, NT, 0, stream>>>(partial, acc, out);
}